// Round 6
// baseline (271.795 us; speedup 1.0000x reference)
//
#include <hip/hip_runtime.h>

// Problem constants (fixed by setup_inputs):
//   a_arc, s_arc : [64, 1024, 1024] f32
//   adds, pos    : [64, 1024] int32 in [0, 50)
constexpr int NPOS  = 50;
constexpr int NBINS = NPOS * NPOS;   // 2500
constexpr int SL    = 1024;
constexpr int BZ    = 64;
constexpr float ALPHA = 0.3f;

// ---------------- hist kernel config ----------------
constexpr int H_THREADS = 128;                 // 2 adjacent columns per thread
constexpr int H_COLS    = 2 * H_THREADS;       // 256 columns per block
constexpr int COLCHUNKS = SL / H_COLS;         // 4
constexpr int ROWSPLITS = 2;
constexpr int H_ROWS    = SL / ROWSPLITS;      // 512 rows per block
constexpr int H_BLOCKS  = BZ * COLCHUNKS * ROWSPLITS;   // 512 (2 blocks/CU)

// ---------------- apply kernel config ----------------
constexpr int A_THREADS       = 256;
constexpr int ROWS_PER_BLOCK  = 32;
constexpr int BLOCKS_PER_B    = SL / ROWS_PER_BLOCK;    // 32
constexpr int A_BLOCKS        = BZ * BLOCKS_PER_B;      // 2048

// ---------------------------------------------------------------------------
// Kernel 1: histogram with REGISTER accumulation (no per-element LDS ops).
// Rounds 3-5 showed the per-element LDS RMW chain (alias-serialized ds_read
// after ds_write) pins hist at ~100us regardless of load width / ILP /
// occupancy. Fix: counting-sort this block's 512 rows by row-bin p; for each
// p, sum its ~10 rows into registers (8-wide unrolled independent loads),
// then ONE plain ds_write to the exclusive slot acc[p][tid]. Every wave
// walks all rows (threads own columns), so no cross-wave group splits.
// ---------------------------------------------------------------------------
__global__ __launch_bounds__(H_THREADS) void hist_kernel(
    const float* __restrict__ a, const int* __restrict__ adds,
    float* __restrict__ g_hist) {
  __shared__ float accA[NPOS][H_THREADS];   // 25.6 KB (even columns)
  __shared__ float accB[NPOS][H_THREADS];   // 25.6 KB (odd  columns)
  __shared__ int   adds_s[SL];              // 4 KB
  __shared__ int   orderR[H_ROWS];          // 2 KB: rows sorted by bin p
  __shared__ int   cntR[NPOS], offRs[NPOS], offRm[NPOS];
  __shared__ int   cnt2[NPOS], off2s[NPOS], off2m[NPOS];
  __shared__ int   order2[H_COLS];          // columns sorted by bin q

  const int tid    = threadIdx.x;
  const int b      = blockIdx.x / (COLCHUNKS * ROWSPLITS);
  const int rem    = blockIdx.x % (COLCHUNKS * ROWSPLITS);
  const int cc     = rem / ROWSPLITS;
  const int rsplit = rem % ROWSPLITS;
  const int i0     = rsplit * H_ROWS;

  // --- stage adds row; zero counters ---
  {
    const int4* src = (const int4*)(adds + (size_t)b * SL);
    ((int4*)adds_s)[tid]             = src[tid];
    ((int4*)adds_s)[tid + H_THREADS] = src[tid + H_THREADS];
  }
  if (tid < NPOS) { cntR[tid] = 0; cnt2[tid] = 0; }
  __syncthreads();

  const int j0 = cc * H_COLS + 2 * tid;     // this thread's even column
  const int q0 = adds_s[j0];                // its two fixed column-bins
  const int q1 = adds_s[j0 + 1];

  // --- counting sorts: rows by p, columns by q (verified pattern) ---
  for (int r = tid; r < H_ROWS; r += H_THREADS)
    atomicAdd(&cntR[adds_s[i0 + r]], 1);
  atomicAdd(&cnt2[q0], 1);
  atomicAdd(&cnt2[q1], 1);
  __syncthreads();
  if (tid == 0) {                 // wave 0: row prefix
    int run = 0;
    for (int c = 0; c < NPOS; ++c) { offRs[c] = run; offRm[c] = run; run += cntR[c]; }
  } else if (tid == 64) {         // wave 1: column prefix, concurrent
    int run = 0;
    for (int c = 0; c < NPOS; ++c) { off2s[c] = run; off2m[c] = run; run += cnt2[c]; }
  }
  __syncthreads();
  for (int r = tid; r < H_ROWS; r += H_THREADS)
    orderR[atomicAdd(&offRm[adds_s[i0 + r]], 1)] = r;
  order2[atomicAdd(&off2m[q0], 1)] = 2 * tid;
  order2[atomicAdd(&off2m[q1], 1)] = 2 * tid + 1;
  __syncthreads();

  // --- main loop: per row-bin p, register-accumulate its rows ---
  const float2* __restrict__ P =
      (const float2*)(a + ((size_t)b * SL + i0) * SL + j0);
  constexpr int RS = SL / 2;                // row stride in float2 units

  for (int p = 0; p < NPOS; ++p) {
    const int s0 = offRs[p];                // wave-uniform
    const int n  = cntR[p];
    float ax = 0.0f, ay = 0.0f;
    int k = 0;
    for (; k + 8 <= n; k += 8) {            // 8 independent loads in flight
      int rr[8];
      #pragma unroll
      for (int u = 0; u < 8; ++u) rr[u] = orderR[s0 + k + u];
      float2 vv[8];
      #pragma unroll
      for (int u = 0; u < 8; ++u) vv[u] = P[(size_t)rr[u] * RS];
      #pragma unroll
      for (int u = 0; u < 8; ++u) { ax += vv[u].x; ay += vv[u].y; }
    }
    for (; k < n; ++k) {
      const int r = orderR[s0 + k];
      const float2 v = P[(size_t)r * RS];
      ax += v.x; ay += v.y;
    }
    accA[p][tid] = ax;                      // exclusive slot: plain write,
    accB[p][tid] = ay;                      // once per p (50 total)
  }
  __syncthreads();

  // --- reduce: bin (p,q) = sum over this block's columns with q_c == q ---
  // (avg ~5 columns per bin; one global atomic per (block, bin))
  for (int bin = tid; bin < NBINS; bin += H_THREADS) {
    const int p  = bin / NPOS;
    const int qq = bin % NPOS;
    const int s0 = off2s[qq];
    const int n  = cnt2[qq];
    float s = 0.0f;
    for (int k = 0; k < n; ++k) {
      const int c = order2[s0 + k];
      s += (c & 1) ? accB[p][c >> 1] : accA[p][c >> 1];
    }
    atomicAdd(&g_hist[bin], s);
  }
}

// ---------------------------------------------------------------------------
// Kernel 2: out = s_arc + ALPHA * sigmoid(hist)[pos[b,i]*50 + pos[b,j]]
// Measured at ~6.1 TB/s (HBM roofline) — unchanged from the passing version.
// ---------------------------------------------------------------------------
__global__ __launch_bounds__(A_THREADS) void apply_kernel(
    const float* __restrict__ s, const int* __restrict__ pos,
    const float* __restrict__ g_hist, float* __restrict__ out) {
  __shared__ float sig[NBINS];
  __shared__ int   pos_s[SL];

  const int tid = threadIdx.x;
  const int b   = blockIdx.x / BLOCKS_PER_B;
  const int i0  = (blockIdx.x % BLOCKS_PER_B) * ROWS_PER_BLOCK;

  ((int4*)pos_s)[tid] = ((const int4*)(pos + (size_t)b * SL))[tid];
  for (int k = tid; k < NBINS; k += A_THREADS) {
    const float h = g_hist[k];
    sig[k] = 1.0f / (1.0f + __expf(-h));
  }
  __syncthreads();

  const int4 pj = ((const int4*)pos_s)[tid];
  const size_t rowoff = ((size_t)b * SL + i0) * SL;
  const float4* __restrict__ srow = (const float4*)(s + rowoff);
  float4* __restrict__ orow = (float4*)(out + rowoff);

  for (int r = 0; r < ROWS_PER_BLOCK; ++r) {
    const int base = pos_s[i0 + r] * NPOS;    // wave-uniform broadcast
    const float4 sv = srow[(size_t)r * (SL / 4) + tid];
    float4 ov;
    ov.x = sv.x + ALPHA * sig[base + pj.x];
    ov.y = sv.y + ALPHA * sig[base + pj.y];
    ov.z = sv.z + ALPHA * sig[base + pj.z];
    ov.w = sv.w + ALPHA * sig[base + pj.w];
    orow[(size_t)r * (SL / 4) + tid] = ov;
  }
}

extern "C" void kernel_launch(void* const* d_in, const int* in_sizes, int n_in,
                              void* d_out, int out_size, void* d_ws, size_t ws_size,
                              hipStream_t stream) {
  const float* a_arc = (const float*)d_in[0];
  const float* s_arc = (const float*)d_in[1];
  const int*   adds  = (const int*)d_in[2];
  const int*   pos   = (const int*)d_in[3];
  float* out    = (float*)d_out;
  float* g_hist = (float*)d_ws;   // NBINS floats = 10 KB scratch

  // d_ws is NOT re-poisoned between timed replays; zero it each call.
  hipMemsetAsync(g_hist, 0, NBINS * sizeof(float), stream);

  hist_kernel <<<H_BLOCKS, H_THREADS, 0, stream>>>(a_arc, adds, g_hist);
  apply_kernel<<<A_BLOCKS, A_THREADS, 0, stream>>>(s_arc, pos, g_hist, out);
}

// Round 7
// 216.372 us; speedup vs baseline: 1.2562x; 1.2562x over previous
//
#include <hip/hip_runtime.h>

// Problem constants (fixed by setup_inputs):
//   a_arc, s_arc : [64, 1024, 1024] f32
//   adds, pos    : [64, 1024] int32 in [0, 50)
constexpr int NPOS  = 50;
constexpr int NBINS = NPOS * NPOS;   // 2500
constexpr int SL    = 1024;
constexpr int BZ    = 64;
constexpr float ALPHA = 0.3f;
constexpr int NSLICE = 4;            // partial-hist slices in d_ws

using f32x4  = __attribute__((ext_vector_type(4))) float;
using bf16x8 = __attribute__((ext_vector_type(8))) short;

// ---------------- hist (MFMA) config ----------------
// score[p,q] = sum_b E_b^T A_b E_b,  E[j,q] = (adds[j]==q), q padded to 64.
// Stage 1: T = A * E via mfma_f32_16x16x32_bf16 (A split hi/lo bf16).
// Stage 2: S += E^T * T via counting-sorted row runs over LDS-resident T.
constexpr int H_THREADS = 128;                    // 2 waves
constexpr int H_ROWS    = 128;                    // rows per block
constexpr int H_RBLKS   = SL / H_ROWS;            // 8
constexpr int KSPLIT    = 2;                      // j-halves
constexpr int H_BLOCKS  = BZ * H_RBLKS * KSPLIT;  // 1024

// ---------------- apply kernel config ----------------
constexpr int A_THREADS      = 256;
constexpr int ROWS_PER_BLOCK = 32;
constexpr int BLOCKS_PER_B   = SL / ROWS_PER_BLOCK;   // 32
constexpr int A_BLOCKS       = BZ * BLOCKS_PER_B;     // 2048

__global__ __launch_bounds__(H_THREADS) void hist_mfma(
    const float* __restrict__ a, const int* __restrict__ adds,
    float* __restrict__ g_hist) {
  __shared__ int   adds_s[SL];          // 4 KB
  __shared__ float T_lds[H_ROWS][66];   // 33.8 KB (pad 64->66: no bank clash)
  __shared__ float acc2[NPOS * 64];     // 12.8 KB partial S (LDS atomics)
  __shared__ int   orderR[H_ROWS];      // rows sorted by p
  __shared__ int   cntR[NPOS], offm[NPOS];

  const int tid   = threadIdx.x;
  const int b     = blockIdx.x >> 4;
  const int rem   = blockIdx.x & 15;
  const int rblk  = rem >> 1;
  const int khalf = rem & 1;
  const int row0  = rblk * H_ROWS;
  const int j0b   = khalf * (SL / KSPLIT);

  // --- stage adds row; zero counters/partials ---
  {
    const int4* src = (const int4*)(adds + (size_t)b * SL);
    ((int4*)adds_s)[tid]             = src[tid];
    ((int4*)adds_s)[tid + H_THREADS] = src[tid + H_THREADS];
  }
  if (tid < NPOS) cntR[tid] = 0;
  for (int k = tid; k < NPOS * 64; k += H_THREADS) acc2[k] = 0.0f;
  __syncthreads();

  // --- counting sort of the block's 128 rows by p = adds[row] ---
  atomicAdd(&cntR[adds_s[row0 + tid]], 1);
  __syncthreads();
  if (tid == 0) {
    int run = 0;
    for (int c = 0; c < NPOS; ++c) { offm[c] = run; run += cntR[c]; }
  }
  __syncthreads();
  orderR[atomicAdd(&offm[adds_s[row0 + tid]], 1)] = tid;
  // (orderR consumed only after the post-mainloop __syncthreads)

  // --- stage 1: T[r, q] = sum_j A[r,j] * (adds[j]==q), q in [0,64) ---
  const int wid = tid >> 6, lane = tid & 63;
  const int kg = lane >> 4, l15 = lane & 15;     // k-group, row/col-in-tile
  const int rowbase = row0 + wid * 64;           // this wave's 64 rows
  const float* __restrict__ Abase = a + (size_t)b * SL * SL;

  f32x4 acc[4][4] = {};                          // [row-tile][q-tile]
  for (int ks = 0; ks < (SL / KSPLIT) / 32; ++ks) {   // 16 K-steps of 32
    const int kk = j0b + ks * 32 + kg * 8;       // this lane's 8 k-indices

    // B fragment: E[kk+e][q], q = qt*16 + l15 (exact 0/1 in bf16)
    int av[8];
    #pragma unroll
    for (int e = 0; e < 8; ++e) av[e] = adds_s[kk + e];
    bf16x8 bq[4];
    #pragma unroll
    for (int qt = 0; qt < 4; ++qt) {
      const int q = qt * 16 + l15;
      #pragma unroll
      for (int e = 0; e < 8; ++e)
        bq[qt][e] = (av[e] == q) ? (short)0x3F80 : (short)0;
    }

    // A fragments (hi/lo bf16 split; truncation — lo captures the residue)
    #pragma unroll
    for (int rt = 0; rt < 4; ++rt) {
      const float* rp = Abase + (size_t)(rowbase + rt * 16 + l15) * SL + kk;
      const float4 va = ((const float4*)rp)[0];
      const float4 vb = ((const float4*)rp)[1];
      const float f[8] = {va.x, va.y, va.z, va.w, vb.x, vb.y, vb.z, vb.w};
      bf16x8 ah, al;
      #pragma unroll
      for (int e = 0; e < 8; ++e) {
        const unsigned u = __builtin_bit_cast(unsigned, f[e]);
        ah[e] = (short)(u >> 16);
        const float hf = __builtin_bit_cast(float, u & 0xFFFF0000u);
        const float lo = f[e] - hf;
        al[e] = (short)(__builtin_bit_cast(unsigned, lo) >> 16);
      }
      #pragma unroll
      for (int qt = 0; qt < 4; ++qt) {
        acc[rt][qt] = __builtin_amdgcn_mfma_f32_16x16x32_bf16(
            ah, bq[qt], acc[rt][qt], 0, 0, 0);
        acc[rt][qt] = __builtin_amdgcn_mfma_f32_16x16x32_bf16(
            al, bq[qt], acc[rt][qt], 0, 0, 0);
      }
    }
  }

  // C/D layout (m89-verified): col = lane&15, row = (lane>>4)*4 + reg
  #pragma unroll
  for (int rt = 0; rt < 4; ++rt)
    #pragma unroll
    for (int qt = 0; qt < 4; ++qt)
      #pragma unroll
      for (int r = 0; r < 4; ++r)
        T_lds[wid * 64 + rt * 16 + kg * 4 + r][qt * 16 + l15] = acc[rt][qt][r];
  __syncthreads();

  // --- stage 2: S[p,q] += sum_{rows with p} T[row,q], via sorted runs ---
  {
    const int q = tid & 63, half = tid >> 6;
    float s = 0.0f;
    int pcur = -1;
    for (int k2 = 0; k2 < 64; ++k2) {
      const int row = orderR[half * 64 + k2];      // wave-uniform
      const int p   = adds_s[row0 + row];          // wave-uniform
      if (p != pcur) {                             // uniform branch
        if (pcur >= 0) atomicAdd(&acc2[pcur * 64 + q], s);
        pcur = p; s = 0.0f;
      }
      s += T_lds[row][q];                          // conflict-free
    }
    if (pcur >= 0) atomicAdd(&acc2[pcur * 64 + q], s);
  }
  __syncthreads();

  // --- flush partial S to one of NSLICE global slices ---
  float* __restrict__ gs = g_hist + (size_t)(blockIdx.x & (NSLICE - 1)) * NBINS;
  for (int bin = tid; bin < NBINS; bin += H_THREADS) {
    const float v = acc2[(bin / NPOS) * 64 + (bin % NPOS)];
    if (v != 0.0f) atomicAdd(&gs[bin], v);
  }
}

// ---------------------------------------------------------------------------
// Kernel 2: out = s_arc + ALPHA * sigmoid(sum_slices hist)[pos-pair bin]
// ---------------------------------------------------------------------------
__global__ __launch_bounds__(A_THREADS) void apply_kernel(
    const float* __restrict__ s, const int* __restrict__ pos,
    const float* __restrict__ g_hist, float* __restrict__ out) {
  __shared__ float sig[NBINS];
  __shared__ int   pos_s[SL];

  const int tid = threadIdx.x;
  const int b   = blockIdx.x / BLOCKS_PER_B;
  const int i0  = (blockIdx.x % BLOCKS_PER_B) * ROWS_PER_BLOCK;

  ((int4*)pos_s)[tid] = ((const int4*)(pos + (size_t)b * SL))[tid];
  for (int k = tid; k < NBINS; k += A_THREADS) {
    const float h = g_hist[k] + g_hist[NBINS + k] +
                    g_hist[2 * NBINS + k] + g_hist[3 * NBINS + k];
    sig[k] = 1.0f / (1.0f + __expf(-h));
  }
  __syncthreads();

  const int4 pj = ((const int4*)pos_s)[tid];
  const size_t rowoff = ((size_t)b * SL + i0) * SL;
  const float4* __restrict__ srow = (const float4*)(s + rowoff);
  float4* __restrict__ orow = (float4*)(out + rowoff);

  for (int r = 0; r < ROWS_PER_BLOCK; ++r) {
    const int base = pos_s[i0 + r] * NPOS;    // wave-uniform broadcast
    const float4 sv = srow[(size_t)r * (SL / 4) + tid];
    float4 ov;
    ov.x = sv.x + ALPHA * sig[base + pj.x];
    ov.y = sv.y + ALPHA * sig[base + pj.y];
    ov.z = sv.z + ALPHA * sig[base + pj.z];
    ov.w = sv.w + ALPHA * sig[base + pj.w];
    orow[(size_t)r * (SL / 4) + tid] = ov;
  }
}

extern "C" void kernel_launch(void* const* d_in, const int* in_sizes, int n_in,
                              void* d_out, int out_size, void* d_ws, size_t ws_size,
                              hipStream_t stream) {
  const float* a_arc = (const float*)d_in[0];
  const float* s_arc = (const float*)d_in[1];
  const int*   adds  = (const int*)d_in[2];
  const int*   pos   = (const int*)d_in[3];
  float* out    = (float*)d_out;
  float* g_hist = (float*)d_ws;   // NSLICE * NBINS floats = 40 KB scratch

  // d_ws is NOT re-poisoned between timed replays; zero it each call.
  hipMemsetAsync(g_hist, 0, NSLICE * NBINS * sizeof(float), stream);

  hist_mfma   <<<H_BLOCKS, H_THREADS, 0, stream>>>(a_arc, adds, g_hist);
  apply_kernel<<<A_BLOCKS, A_THREADS, 0, stream>>>(s_arc, pos, g_hist, out);
}

// Round 8
// 190.493 us; speedup vs baseline: 1.4268x; 1.1359x over previous
//
#include <hip/hip_runtime.h>

// Problem constants (fixed by setup_inputs):
//   a_arc, s_arc : [64, 1024, 1024] f32
//   adds, pos    : [64, 1024] int32 in [0, 50)
constexpr int NPOS  = 50;
constexpr int NBINS = NPOS * NPOS;   // 2500
constexpr int SL    = 1024;
constexpr int BZ    = 64;
constexpr float ALPHA = 0.3f;
constexpr int NSLICE = 4;            // partial-hist slices in d_ws

using f32x4  = __attribute__((ext_vector_type(4))) float;
using bf16x8 = __attribute__((ext_vector_type(8))) short;

// ---------------- hist (MFMA) config ----------------
// score[p,q] = sum_b E_b^T A_b E_b,  E[j,q] = (adds[j]==q), q padded to 64.
// Stage 1: T = A * E via mfma_f32_16x16x32_bf16 (A split hi/lo bf16 - exact).
// Stage 2: S += E^T * T via counting-sorted row runs over LDS-resident T.
// R7 restructure: 4-wave blocks, 64 rows x K=512 -> ~32 KB LDS -> 4-5
// blocks/CU = 16-20 waves/CU (was 4-6), plus 2-deep register ping-pong
// prefetch for MLP. Math identical to the R6 kernel that passed.
constexpr int H_THREADS = 256;                    // 4 waves, 16 rows each
constexpr int H_ROWS    = 64;                     // rows per block
constexpr int KSPLIT    = 2;                      // j-halves (K=512/block)
constexpr int KSTEPS    = (SL / KSPLIT) / 32;     // 16 K-steps of 32
constexpr int H_BLOCKS  = BZ * (SL / H_ROWS) * KSPLIT;  // 2048

// ---------------- apply kernel config ----------------
constexpr int A_THREADS      = 256;
constexpr int ROWS_PER_BLOCK = 32;
constexpr int BLOCKS_PER_B   = SL / ROWS_PER_BLOCK;   // 32
constexpr int A_BLOCKS       = BZ * BLOCKS_PER_B;     // 2048

__global__ __launch_bounds__(H_THREADS) void hist_mfma(
    const float* __restrict__ a, const int* __restrict__ adds,
    float* __restrict__ g_hist) {
  __shared__ int   adds_s[SL];           // 4 KB
  __shared__ float T_lds[H_ROWS][66];    // 16.9 KB (pad 64->66: bank-safe)
  __shared__ float acc2[NPOS * 52];      // 10.4 KB partial S
  __shared__ int   orderR[H_ROWS];       // rows sorted by p
  __shared__ int   cntR[NPOS], offm[NPOS];

  const int tid   = threadIdx.x;
  const int b     = blockIdx.x >> 5;     // 32 blocks per batch
  const int rem   = blockIdx.x & 31;
  const int rblk  = rem >> 1;            // 0..15
  const int khalf = rem & 1;
  const int row0  = rblk * H_ROWS;
  const int j0b   = khalf * (SL / KSPLIT);

  // --- stage adds row; zero counters/partials ---
  ((int4*)adds_s)[tid] = ((const int4*)(adds + (size_t)b * SL))[tid];
  for (int k = tid; k < NPOS * 52; k += H_THREADS) acc2[k] = 0.0f;
  if (tid < NPOS) cntR[tid] = 0;
  __syncthreads();

  // --- counting sort of the block's 64 rows by p = adds[row] ---
  if (tid < H_ROWS) atomicAdd(&cntR[adds_s[row0 + tid]], 1);
  __syncthreads();
  if (tid == 0) {
    int run = 0;
    for (int c = 0; c < NPOS; ++c) { offm[c] = run; run += cntR[c]; }
  }
  __syncthreads();
  if (tid < H_ROWS)
    orderR[atomicAdd(&offm[adds_s[row0 + tid]], 1)] = tid;
  // (orderR consumed only after the post-stage1 __syncthreads)

  // --- stage 1: T[r,q] = sum_j A[r,j] * (adds[j]==q), q in [0,64) ---
  const int wid = tid >> 6, lane = tid & 63;
  const int kg = lane >> 4, l15 = lane & 15;
  const float* __restrict__ Arow =
      a + ((size_t)b * SL + row0 + wid * 16 + l15) * SL + j0b + kg * 8;

  struct PF { float4 va, vb; int4 w0, w1; };
  auto loadpf = [&](PF& buf, int ks) {
    const float* p_ = Arow + ks * 32;
    buf.va = ((const float4*)p_)[0];
    buf.vb = ((const float4*)p_)[1];
    const int kkl = j0b + ks * 32 + kg * 8;
    buf.w0 = *(const int4*)&adds_s[kkl];
    buf.w1 = *(const int4*)&adds_s[kkl + 4];
  };

  f32x4 acc[4] = {};   // one per q-tile
  auto compute = [&](const PF& buf) {
    const float f[8] = {buf.va.x, buf.va.y, buf.va.z, buf.va.w,
                        buf.vb.x, buf.vb.y, buf.vb.z, buf.vb.w};
    const int av[8] = {buf.w0.x, buf.w0.y, buf.w0.z, buf.w0.w,
                       buf.w1.x, buf.w1.y, buf.w1.z, buf.w1.w};
    bf16x8 ah, al;
    #pragma unroll
    for (int e = 0; e < 8; ++e) {
      const unsigned u = __builtin_bit_cast(unsigned, f[e]);
      ah[e] = (short)(u >> 16);
      const float hf = __builtin_bit_cast(float, u & 0xFFFF0000u);
      const float lo = f[e] - hf;                  // exact residue
      al[e] = (short)(__builtin_bit_cast(unsigned, lo) >> 16);
    }
    #pragma unroll
    for (int qt = 0; qt < 4; ++qt) {
      const int q = qt * 16 + l15;
      bf16x8 bq;
      #pragma unroll
      for (int e = 0; e < 8; ++e)
        bq[e] = (av[e] == q) ? (short)0x3F80 : (short)0;
      acc[qt] = __builtin_amdgcn_mfma_f32_16x16x32_bf16(ah, bq, acc[qt], 0, 0, 0);
      acc[qt] = __builtin_amdgcn_mfma_f32_16x16x32_bf16(al, bq, acc[qt], 0, 0, 0);
    }
  };

  PF pfA, pfB;                       // named ping-pong: static indexing
  loadpf(pfA, 0);
  for (int ks = 0; ks < KSTEPS; ks += 2) {
    loadpf(pfB, ks + 1);             // in flight during compute(pfA)
    compute(pfA);
    if (ks + 2 < KSTEPS) loadpf(pfA, ks + 2);
    compute(pfB);
  }

  // C/D layout (m89/R6-verified): col = lane&15, row = (lane>>4)*4 + reg
  #pragma unroll
  for (int qt = 0; qt < 4; ++qt)
    #pragma unroll
    for (int r = 0; r < 4; ++r)
      T_lds[wid * 16 + kg * 4 + r][qt * 16 + l15] = acc[qt][r];
  __syncthreads();

  // --- stage 2: S[p,q] += sum_{rows with p} T[row,q], via sorted runs ---
  {
    const int q = tid & 63, quarter = tid >> 6;   // wave == quarter
    float s = 0.0f;
    int pcur = -1;
    for (int k2 = 0; k2 < H_ROWS / 4; ++k2) {
      const int row = orderR[quarter * (H_ROWS / 4) + k2];  // wave-uniform
      const int p   = adds_s[row0 + row];                   // wave-uniform
      if (p != pcur) {                                      // uniform branch
        if (pcur >= 0 && q < NPOS) atomicAdd(&acc2[pcur * 52 + q], s);
        pcur = p; s = 0.0f;
      }
      s += T_lds[row][q];                                   // conflict-free
    }
    if (pcur >= 0 && q < NPOS) atomicAdd(&acc2[pcur * 52 + q], s);
  }
  __syncthreads();

  // --- flush partial S to one of NSLICE global slices ---
  float* __restrict__ gs = g_hist + (size_t)(blockIdx.x & (NSLICE - 1)) * NBINS;
  for (int bin = tid; bin < NBINS; bin += H_THREADS) {
    const float v = acc2[(bin / NPOS) * 52 + (bin % NPOS)];
    if (v != 0.0f) atomicAdd(&gs[bin], v);
  }
}

// ---------------------------------------------------------------------------
// Kernel 2: out = s_arc + ALPHA * sigmoid(sum_slices hist)[pos-pair bin]
// Measured ~6.1 TB/s (HBM roofline) — unchanged.
// ---------------------------------------------------------------------------
__global__ __launch_bounds__(A_THREADS) void apply_kernel(
    const float* __restrict__ s, const int* __restrict__ pos,
    const float* __restrict__ g_hist, float* __restrict__ out) {
  __shared__ float sig[NBINS];
  __shared__ int   pos_s[SL];

  const int tid = threadIdx.x;
  const int b   = blockIdx.x / BLOCKS_PER_B;
  const int i0  = (blockIdx.x % BLOCKS_PER_B) * ROWS_PER_BLOCK;

  ((int4*)pos_s)[tid] = ((const int4*)(pos + (size_t)b * SL))[tid];
  for (int k = tid; k < NBINS; k += A_THREADS) {
    const float h = g_hist[k] + g_hist[NBINS + k] +
                    g_hist[2 * NBINS + k] + g_hist[3 * NBINS + k];
    sig[k] = 1.0f / (1.0f + __expf(-h));
  }
  __syncthreads();

  const int4 pj = ((const int4*)pos_s)[tid];
  const size_t rowoff = ((size_t)b * SL + i0) * SL;
  const float4* __restrict__ srow = (const float4*)(s + rowoff);
  float4* __restrict__ orow = (float4*)(out + rowoff);

  for (int r = 0; r < ROWS_PER_BLOCK; ++r) {
    const int base = pos_s[i0 + r] * NPOS;    // wave-uniform broadcast
    const float4 sv = srow[(size_t)r * (SL / 4) + tid];
    float4 ov;
    ov.x = sv.x + ALPHA * sig[base + pj.x];
    ov.y = sv.y + ALPHA * sig[base + pj.y];
    ov.z = sv.z + ALPHA * sig[base + pj.z];
    ov.w = sv.w + ALPHA * sig[base + pj.w];
    orow[(size_t)r * (SL / 4) + tid] = ov;
  }
}

extern "C" void kernel_launch(void* const* d_in, const int* in_sizes, int n_in,
                              void* d_out, int out_size, void* d_ws, size_t ws_size,
                              hipStream_t stream) {
  const float* a_arc = (const float*)d_in[0];
  const float* s_arc = (const float*)d_in[1];
  const int*   adds  = (const int*)d_in[2];
  const int*   pos   = (const int*)d_in[3];
  float* out    = (float*)d_out;
  float* g_hist = (float*)d_ws;   // NSLICE * NBINS floats = 40 KB scratch

  // d_ws is NOT re-poisoned between timed replays; zero it each call.
  hipMemsetAsync(g_hist, 0, NSLICE * NBINS * sizeof(float), stream);

  hist_mfma   <<<H_BLOCKS, H_THREADS, 0, stream>>>(a_arc, adds, g_hist);
  apply_kernel<<<A_BLOCKS, A_THREADS, 0, stream>>>(s_arc, pos, g_hist, out);
}